// Round 1
// baseline (211.122 us; speedup 1.0000x reference)
//
#include <hip/hip_runtime.h>
#include <math.h>

// Problem constants (see reference): B=512 queries, N=131072 bank items,
// D=256 features, 64 bags, 96x96 grid, threshold dist^2 < 4, temp 0.2.
#define NBAGS  64
#define BAGCAP 96      // max queries per bag; actual max ~25 for binomial(512,1/64)
#define D4     64      // D/4 float4s per row

// K1: bucket queries by bag id (packed entry: b<<14 | x<<7 | y), zero d_out.
// Single block, B threads.
__global__ void k_init(const int* __restrict__ bag_idx,
                       const int* __restrict__ x_coord,
                       const int* __restrict__ y_coord,
                       float* __restrict__ out,
                       int* __restrict__ bucket_g,   // [NBAGS*BAGCAP]
                       int* __restrict__ counts_g,   // [NBAGS]
                       int B)
{
    __shared__ int cnt[NBAGS];
    int tid = threadIdx.x;
    if (tid < NBAGS) cnt[tid] = 0;
    __syncthreads();
    if (tid < B) {
        int bag  = bag_idx[tid];
        int slot = atomicAdd(&cnt[bag], 1);
        if (slot < BAGCAP) {
            int e = (tid << 14) | (x_coord[tid] << 7) | y_coord[tid];
            bucket_g[bag * BAGCAP + slot] = e;
        }
        out[tid] = 0.0f;   // harness poisons d_out to 0xAA every call
    }
    __syncthreads();
    if (tid < NBAGS) counts_g[tid] = min(cnt[tid], BAGCAP);
}

// K2: one thread per memory item (grid-stride). Check only queries in the
// item's bag (~8 avg). On the rare mask hit (~900 total across the whole
// grid), compute |q_b|^2 and q_b . m_j with float4 loads and accumulate
// exp((qm/|q_b|)/0.2) into out[b].
__global__ void k_scan(const float* __restrict__ q,
                       const float* __restrict__ memory,
                       const int* __restrict__ bag_idxs,
                       const int* __restrict__ x_coords,
                       const int* __restrict__ y_coords,
                       const int* __restrict__ bucket_g,
                       const int* __restrict__ counts_g,
                       float* __restrict__ out,
                       int N)
{
    __shared__ int s_bucket[NBAGS * BAGCAP];
    __shared__ int s_cnt[NBAGS];
    int tid = threadIdx.x;
    for (int i = tid; i < NBAGS * BAGCAP; i += blockDim.x)
        s_bucket[i] = bucket_g[i];
    if (tid < NBAGS) s_cnt[tid] = counts_g[tid];
    __syncthreads();

    const float4* q4 = (const float4*)q;
    const float4* m4 = (const float4*)memory;

    int stride = gridDim.x * blockDim.x;
    for (int j = blockIdx.x * blockDim.x + tid; j < N; j += stride) {
        int jb = bag_idxs[j];
        int jx = x_coords[j];
        int jy = y_coords[j];
        int n    = s_cnt[jb];
        int base = jb * BAGCAP;
        for (int i = 0; i < n; ++i) {
            int e  = s_bucket[base + i];
            int dx = ((e >> 7) & 127) - jx;
            int dy = (e & 127) - jy;
            int d2 = dx * dx + dy * dy;
            // coords are small ints -> reference's fp32 d2 is exact integer;
            // (d2 > 0 && d2 < 4) reproduces (d2 > 0.0f && d2 < 4.0f) exactly.
            if (d2 > 0 && d2 < 4) {
                int b = e >> 14;
                const float4* qr = q4 + b * D4;
                const float4* mr = m4 + (long)j * D4;
                float qq = 0.0f, qm = 0.0f;
                #pragma unroll 8
                for (int k = 0; k < D4; ++k) {
                    float4 a = qr[k];
                    float4 m = mr[k];
                    qq += a.x * a.x + a.y * a.y + a.z * a.z + a.w * a.w;
                    qm += a.x * m.x + a.y * m.y + a.z * m.z + a.w * m.w;
                }
                float l = qm / sqrtf(qq);      // q_b normalized dot m_j
                float s = expf(l / 0.2f);      // exp(l / TEMP)
                atomicAdd(&out[b], s);
            }
        }
    }
}

extern "C" void kernel_launch(void* const* d_in, const int* in_sizes, int n_in,
                              void* d_out, int out_size, void* d_ws, size_t ws_size,
                              hipStream_t stream)
{
    const float* q        = (const float*)d_in[0];
    const float* memory   = (const float*)d_in[1];
    const int*   bag_idx  = (const int*)d_in[2];
    const int*   x_coord  = (const int*)d_in[3];
    const int*   y_coord  = (const int*)d_in[4];
    const int*   bag_idxs = (const int*)d_in[5];
    const int*   x_coords = (const int*)d_in[6];
    const int*   y_coords = (const int*)d_in[7];
    float*       out      = (float*)d_out;

    int B = in_sizes[2];   // 512
    int N = in_sizes[5];   // 131072

    int* bucket_g = (int*)d_ws;                 // NBAGS*BAGCAP ints
    int* counts_g = bucket_g + NBAGS * BAGCAP;  // NBAGS ints
    // ws needed: (64*96 + 64)*4 = ~25 KB << ws_size

    k_init<<<1, B, 0, stream>>>(bag_idx, x_coord, y_coord, out,
                                bucket_g, counts_g, B);

    int threads = 256;
    int blocks  = (N + threads - 1) / threads;  // 512
    k_scan<<<blocks, threads, 0, stream>>>(q, memory, bag_idxs, x_coords,
                                           y_coords, bucket_g, counts_g,
                                           out, N);
}

// Round 2
// 207.215 us; speedup vs baseline: 1.0189x; 1.0189x over previous
//
#include <hip/hip_runtime.h>
#include <math.h>

// Problem constants: B=512 queries, N=131072 bank items, D=256 features,
// 64 bags, 96x96 grid, hit iff same bag && 0 < dx^2+dy^2 < 4, temp 0.2.
//
// Algorithm: mask-first. Expected hits ~= 512*131072 * (1/64) * (8/9216)
// ~= 900 total, so we never touch the 134 MB `memory` array except for
// ~900 rows. Coords are small ints -> integer d2 test is bit-exact vs the
// reference's fp32 expansion.
#define NBAGS  64
#define BAGCAP 40      // max queries/bag; binomial(512,1/64) max ~20, 40 is >8 sigma
#define TBL    (BAGCAP * NBAGS)
#define D4     64      // D/4 float4s per feature row

// K1 (1 block, 512 threads): zero d_out (harness poisons it), bucket the 512
// queries by bag into a TRANSPOSED table tbl[slot*64 + bag] (bank = bag%32 ->
// at most 2-way LDS alias for readers, which is free), write table+counts to ws.
// entry packing: (query_idx << 14) | (x << 7) | y
__global__ void k_init(const int* __restrict__ bag_idx,
                       const int* __restrict__ x_coord,
                       const int* __restrict__ y_coord,
                       float* __restrict__ out,
                       int* __restrict__ table_g,   // [TBL + NBAGS]
                       int B)
{
    __shared__ int cnt[NBAGS];
    __shared__ int tbl[TBL];
    int tid = threadIdx.x;
    if (tid < NBAGS) cnt[tid] = 0;
    __syncthreads();
    if (tid < B) {
        int bag  = bag_idx[tid];
        int slot = atomicAdd(&cnt[bag], 1);
        if (slot < BAGCAP)
            tbl[slot * NBAGS + bag] = (tid << 14) | (x_coord[tid] << 7) | y_coord[tid];
        out[tid] = 0.0f;
    }
    __syncthreads();
    for (int i = tid; i < TBL; i += blockDim.x)
        table_g[i] = tbl[i];          // unused slots are garbage; readers bound by cnt
    if (tid < NBAGS) table_g[TBL + tid] = min(cnt[tid], BAGCAP);
}

// K2: one thread per memory item. Check only the ~8 queries sharing the
// item's bag (LDS table, conflict-free transposed layout). On a hit
// (~900 device-wide), fused-normalized dot via float4 + one atomicAdd.
__global__ void k_scan(const float* __restrict__ q,
                       const float* __restrict__ memory,
                       const int* __restrict__ bag_idxs,
                       const int* __restrict__ x_coords,
                       const int* __restrict__ y_coords,
                       const int* __restrict__ table_g,
                       float* __restrict__ out,
                       int N)
{
    __shared__ int s_tbl[TBL];
    __shared__ int s_cnt[NBAGS];
    int tid = threadIdx.x;
    #pragma unroll
    for (int i = tid; i < TBL; i += 256)
        s_tbl[i] = table_g[i];
    if (tid < NBAGS) s_cnt[tid] = table_g[TBL + tid];
    __syncthreads();

    int j = blockIdx.x * blockDim.x + tid;
    if (j >= N) return;

    int jb = bag_idxs[j];
    int jx = x_coords[j];
    int jy = y_coords[j];
    int n  = s_cnt[jb];

    const float4* q4 = (const float4*)q;
    const float4* m4 = (const float4*)memory;

    for (int i = 0; i < n; ++i) {
        int e  = s_tbl[i * NBAGS + jb];   // bank = jb%32 -> <=2-way alias (free)
        int dx = ((e >> 7) & 127) - jx;
        int dy = (e & 127) - jy;
        int d2 = dx * dx + dy * dy;
        if (d2 > 0 && d2 < 4) {           // exact vs reference's fp32 d2 test
            int b = e >> 14;
            const float4* qr = q4 + b * D4;
            const float4* mr = m4 + (long)j * D4;
            float qq = 0.0f, qm = 0.0f;
            #pragma unroll 8
            for (int k = 0; k < D4; ++k) {
                float4 a = qr[k];
                float4 m = mr[k];
                qq += a.x * a.x + a.y * a.y + a.z * a.z + a.w * a.w;
                qm += a.x * m.x + a.y * m.y + a.z * m.z + a.w * m.w;
            }
            float l = qm / sqrtf(qq);     // normalize(q) . m_j
            atomicAdd(&out[b], expf(l * 5.0f));   // exp(l / 0.2)
        }
    }
}

extern "C" void kernel_launch(void* const* d_in, const int* in_sizes, int n_in,
                              void* d_out, int out_size, void* d_ws, size_t ws_size,
                              hipStream_t stream)
{
    const float* q        = (const float*)d_in[0];
    const float* memory   = (const float*)d_in[1];
    const int*   bag_idx  = (const int*)d_in[2];
    const int*   x_coord  = (const int*)d_in[3];
    const int*   y_coord  = (const int*)d_in[4];
    const int*   bag_idxs = (const int*)d_in[5];
    const int*   x_coords = (const int*)d_in[6];
    const int*   y_coords = (const int*)d_in[7];
    float*       out      = (float*)d_out;

    int B = in_sizes[2];   // 512
    int N = in_sizes[5];   // 131072

    int* table_g = (int*)d_ws;   // TBL + NBAGS ints = ~10.5 KB << ws_size

    k_init<<<1, B, 0, stream>>>(bag_idx, x_coord, y_coord, out, table_g, B);

    int threads = 256;
    int blocks  = (N + threads - 1) / threads;  // 512
    k_scan<<<blocks, threads, 0, stream>>>(q, memory, bag_idxs, x_coords,
                                           y_coords, table_g, out, N);
}

// Round 3
// 204.348 us; speedup vs baseline: 1.0332x; 1.0140x over previous
//
#include <hip/hip_runtime.h>
#include <math.h>

// Problem: B=512 queries, N=131072 bank items, D=256, 64 bags, 96x96 grid,
// hit iff same bag && 0 < dx^2+dy^2 < 4 (the 8-neighborhood), temp 0.2.
//
// Mask-first algorithm: expected hits = 512*131072*(1/64)*(8/9216) ~= 900
// device-wide, so we touch only ~900 of the 131072 memory rows (~0.9 MB of
// the 134 MB array). Coords are small ints -> integer d2 test is bit-exact
// vs the reference's fp32 squared-distance expansion.
//
// Round-3 structure: ONE fused kernel. Each block rebuilds the 64-bag bucket
// table in LDS from the raw 6 KB query metadata (cheaper than a producer
// kernel + global round-trip + stream dependency). d_out zeroed via a
// graph-capturable hipMemsetAsync.
#define NBAGS  64
#define BAGCAP 40      // max queries/bag; binomial(512,1/64) max ~20; 40 is >8 sigma
#define TBL    (BAGCAP * NBAGS)
#define D4     64      // D/4 float4s per feature row

__global__ void __launch_bounds__(256)
k_fused(const float* __restrict__ q,
        const float* __restrict__ memory,
        const int* __restrict__ bag_idx,    // [B] query bag
        const int* __restrict__ x_coord,    // [B]
        const int* __restrict__ y_coord,    // [B]
        const int* __restrict__ bag_idxs,   // [N] bank bag
        const int* __restrict__ x_coords,   // [N]
        const int* __restrict__ y_coords,   // [N]
        float* __restrict__ out,            // [B], pre-zeroed by memset
        int B, int N)
{
    __shared__ int s_cnt[NBAGS];
    __shared__ int s_tbl[TBL];   // transposed: tbl[slot*64+bag] -> bank=bag%32,
                                 // readers at fixed slot alias <=2-way (free)
    int tid = threadIdx.x;
    if (tid < NBAGS) s_cnt[tid] = 0;
    __syncthreads();

    // Build the bag->queries table from raw metadata (6 KB, L2-hot).
    // entry packing: (query_idx << 14) | (x << 7) | y
    for (int i = tid; i < B; i += 256) {
        int bag  = bag_idx[i];
        int slot = atomicAdd(&s_cnt[bag], 1);
        if (slot < BAGCAP)
            s_tbl[slot * NBAGS + bag] = (i << 14) | (x_coord[i] << 7) | y_coord[i];
    }
    __syncthreads();

    int j = blockIdx.x * 256 + tid;
    if (j >= N) return;

    int jb = bag_idxs[j];
    int jx = x_coords[j];
    int jy = y_coords[j];
    int n  = min(s_cnt[jb], BAGCAP);   // ~8 avg

    const float4* q4 = (const float4*)q;
    const float4* m4 = (const float4*)memory;

    for (int i = 0; i < n; ++i) {
        int e  = s_tbl[i * NBAGS + jb];
        int dx = ((e >> 7) & 127) - jx;
        int dy = (e & 127) - jy;
        int d2 = dx * dx + dy * dy;
        if (d2 > 0 && d2 < 4) {            // exact vs reference's fp32 test
            int b = e >> 14;
            const float4* qr = q4 + b * D4;
            const float4* mr = m4 + (long)j * D4;
            float qq = 0.0f, qm = 0.0f;    // fold normalize(q) into the dot
            #pragma unroll 8
            for (int k = 0; k < D4; ++k) {
                float4 a = qr[k];
                float4 m = mr[k];
                qq += a.x * a.x + a.y * a.y + a.z * a.z + a.w * a.w;
                qm += a.x * m.x + a.y * m.y + a.z * m.z + a.w * m.w;
            }
            float l = qm / sqrtf(qq);              // qn . m_j
            atomicAdd(&out[b], expf(l * 5.0f));    // exp(l / 0.2), ~900 device-wide
        }
    }
}

extern "C" void kernel_launch(void* const* d_in, const int* in_sizes, int n_in,
                              void* d_out, int out_size, void* d_ws, size_t ws_size,
                              hipStream_t stream)
{
    const float* q        = (const float*)d_in[0];
    const float* memory   = (const float*)d_in[1];
    const int*   bag_idx  = (const int*)d_in[2];
    const int*   x_coord  = (const int*)d_in[3];
    const int*   y_coord  = (const int*)d_in[4];
    const int*   bag_idxs = (const int*)d_in[5];
    const int*   x_coords = (const int*)d_in[6];
    const int*   y_coords = (const int*)d_in[7];
    float*       out      = (float*)d_out;

    int B = in_sizes[2];   // 512
    int N = in_sizes[5];   // 131072

    // d_out is poisoned to 0xAA before every timed call; zero it via a
    // capturable async memset (becomes a graph memset node).
    hipMemsetAsync(out, 0, (size_t)out_size * sizeof(float), stream);

    int threads = 256;
    int blocks  = (N + threads - 1) / threads;  // 512
    k_fused<<<blocks, threads, 0, stream>>>(q, memory, bag_idx, x_coord, y_coord,
                                            bag_idxs, x_coords, y_coords,
                                            out, B, N);
}